// Round 5
// baseline (240.589 us; speedup 1.0000x reference)
//
#include <hip/hip_runtime.h>
#include <hip/hip_bf16.h>

#define NB 128        // batch B
#define NMEM 100000   // N
#define ND 128        // D
constexpr float K2 = 20.6099442241331655f;   // log2(e)/T  (T=0.07)

constexpr int LROW = ND + 8;              // xs LDS row: 136 bf16 = 272 B
constexpr int NTP = NMEM / 32;            // 3125 pair-tiles of 32 n-cols (exact)
constexpr int GRID = 782;                 // ceil(3125/4): ONE pair-tile per wave,
                                          // all blocks co-resident (3-4 blk/CU)
constexpr int NWAVES = GRID * 4;          // 3128
constexpr int ZSTRIDE = 16;               // zbuf slots 64 B apart

typedef __attribute__((ext_vector_type(8))) __bf16 bf16x8;
typedef __attribute__((ext_vector_type(4))) float f32x4;
struct bf4 { __bf16 a, b, c, d; };

// A = mem rows (n), B = x rows (b).
// A-frag: A[n=lane&15][k=q*8+j]; B-frag: B[b=lane&15][k=q*8+j]
// C/D: col(b)=lane&15, row(n)=q*4+r   [HW-verified m89/m91]
// Line discipline (round-4 win, kept): each 128B out-line = two 64B nt stores
// back-to-back from one wave; no L2 allocation, no half-dirty evictions.
// Round-5 change: ab[2][4] staged once, acc streamed per-mt (peak VGPR down),
// grid sized so every wave owns exactly one tile and ALL are resident.
template<bool PASS2>
__global__ __launch_bounds__(256, 2) void nce_wave(
    const float* __restrict__ x,
    const int* __restrict__ labels,
    const float* __restrict__ mem_da,
    float* __restrict__ zbuf,
    float* __restrict__ out,
    float* __restrict__ maskout)
{
  __shared__ __bf16 xs[NB * LROW];   // 34816 B
  __shared__ float aux[NB];          // pass1: lbl_b; pass2: -log2(Z_b)
  __shared__ float zl[NB];           // pass1 block Z partials

  const int tid = threadIdx.x;

  // ---- one-time stage: x -> bf16 LDS (4 chunks of 4 float4: 16-reg spike) ----
  const float4* x4 = (const float4*)x;
  #pragma unroll
  for (int c = 0; c < 4; ++c) {
    float4 xv[4];
    #pragma unroll
    for (int i = 0; i < 4; ++i) xv[i] = x4[tid + (c * 4 + i) * 256];
    #pragma unroll
    for (int i = 0; i < 4; ++i) {
      int g4 = tid + (c * 4 + i) * 256;
      *(bf4*)&xs[(g4 >> 5) * LROW + (g4 & 31) * 4] =
          bf4{(__bf16)xv[i].x, (__bf16)xv[i].y, (__bf16)xv[i].z, (__bf16)xv[i].w};
    }
  }
  if (tid < NB) {
    if (PASS2) aux[tid] = -__log2f(zbuf[tid * ZSTRIDE]);
    else { aux[tid] = (float)labels[tid]; zl[tid] = 0.f; }
  }
  __syncthreads();                   // the ONLY barrier before the wave loop

  const int wid = tid >> 6, lane = tid & 63, q = lane >> 4, l16 = lane & 15;
  const int wgid = blockIdx.x * 4 + wid;

  // per-lane b-row constants, hoisted: b = mt*16 + l16
  float lblb[8];
  #pragma unroll
  for (int mt = 0; mt < 8; ++mt) lblb[mt] = aux[mt * 16 + l16];

  float zacc[8];
  #pragma unroll
  for (int mt = 0; mt < 8; ++mt) zacc[mt] = 0.f;

  // ---- wave loop: exactly one pair-tile per wave (waves 3125..3127 idle) ----
  for (int t = wgid; t < NTP; t += NWAVES) {
    // A fragments for BOTH halves staged once: 32 VGPRs
    bf16x8 ab[2][4];
    float ln[2];
    #pragma unroll
    for (int h = 0; h < 2; ++h) {
      const float* rowp = mem_da + (size_t)(t * 32 + h * 16 + l16) * 129;
      if (!PASS2) ln[h] = rowp[0];                              // bank label
      #pragma unroll
      for (int kc = 0; kc < 4; ++kc) {
        float tmp[8];
        __builtin_memcpy(tmp, rowp + 1 + kc * 32 + q * 8, 32);
        #pragma unroll
        for (int j = 0; j < 8; ++j) ab[h][kc][j] = (__bf16)tmp[j];
      }
    }

    // labels of the 32 n-rows live in lanes 0..15 of each 16-group
    float ml[2][4];
    if (!PASS2) {
      #pragma unroll
      for (int h = 0; h < 2; ++h)
        #pragma unroll
        for (int r = 0; r < 4; ++r) ml[h][r] = __shfl(ln[h], q * 4 + r, 16);
    }

    // ---- streamed mt: one acc pair live; xb read once feeds both halves ----
    #pragma unroll
    for (int mt = 0; mt < 8; ++mt) {
      f32x4 a0 = (f32x4){0.f, 0.f, 0.f, 0.f};
      f32x4 a1 = (f32x4){0.f, 0.f, 0.f, 0.f};
      #pragma unroll
      for (int kc = 0; kc < 4; ++kc) {
        bf16x8 xb = *(const bf16x8*)&xs[(mt * 16 + l16) * LROW + kc * 32 + q * 8];
        a0 = __builtin_amdgcn_mfma_f32_16x16x32_bf16(ab[0][kc], xb, a0, 0, 0, 0);
        a1 = __builtin_amdgcn_mfma_f32_16x16x32_bf16(ab[1][kc], xb, a1, 0, 0, 0);
      }
      const size_t base = (size_t)(mt * 16 + l16) * NMEM + t * 32 + q * 4;
      if (!PASS2) {
        f32x4 mk0, mk1;
        float zs = 0.f;
        #pragma unroll
        for (int r = 0; r < 4; ++r) {
          zs += exp2f(a0[r] * K2);
          zs += exp2f(a1[r] * K2);
          mk0[r] = (ml[0][r] == lblb[mt]) ? 1.0f : 0.0f;
          mk1[r] = (ml[1][r] == lblb[mt]) ? 1.0f : 0.0f;
        }
        zacc[mt] += zs;
        __builtin_nontemporal_store(mk0, (f32x4*)&maskout[base]);
        __builtin_nontemporal_store(mk1, (f32x4*)&maskout[base + 16]);
      } else {
        f32x4 ov0, ov1;
        #pragma unroll
        for (int r = 0; r < 4; ++r) {
          ov0[r] = exp2f(__builtin_fmaf(a0[r], K2, lblb[mt]));
          ov1[r] = exp2f(__builtin_fmaf(a1[r], K2, lblb[mt]));
        }
        __builtin_nontemporal_store(ov0, (f32x4*)&out[base]);
        __builtin_nontemporal_store(ov1, (f32x4*)&out[base + 16]);
      }
    }
  }

  // ---- pass1 finalize: reduce over q-lanes (xor 16, 32) -> LDS -> global ----
  if (!PASS2) {
    #pragma unroll
    for (int mt = 0; mt < 8; ++mt) {
      float v = zacc[mt];
      v += __shfl_xor(v, 16);
      v += __shfl_xor(v, 32);
      if (lane < 16) atomicAdd(&zl[mt * 16 + lane], v);
    }
    __syncthreads();
    if (tid < NB) atomicAdd(&zbuf[tid * ZSTRIDE], zl[tid]);
  }
}

extern "C" void kernel_launch(void* const* d_in, const int* in_sizes, int n_in,
                              void* d_out, int out_size, void* d_ws, size_t ws_size,
                              hipStream_t stream) {
  const float* x      = (const float*)d_in[0];
  const int* labels   = (const int*)d_in[2];
  const float* mem_da = (const float*)d_in[3];
  float* out     = (float*)d_out;
  float* maskout = out + (size_t)NB * NMEM;
  float* zbuf    = (float*)d_ws;     // 128*16 floats = 8192 B

  hipMemsetAsync(zbuf, 0, NB * ZSTRIDE * sizeof(float), stream);
  nce_wave<false><<<GRID, 256, 0, stream>>>(x, labels, mem_da, zbuf, nullptr, maskout);
  nce_wave<true ><<<GRID, 256, 0, stream>>>(x, labels, mem_da, zbuf, out, nullptr);
}

// Round 6
// 228.216 us; speedup vs baseline: 1.0542x; 1.0542x over previous
//
#include <hip/hip_runtime.h>
#include <hip/hip_bf16.h>

#define NB 128        // batch B
#define NMEM 100000   // N
#define ND 128        // D
constexpr float K2 = 20.6099442241331655f;   // log2(e)/T  (T=0.07)

constexpr int LROW = ND + 8;              // xs LDS row: 136 bf16 = 272 B
constexpr int NTP = NMEM / 32;            // 3125 pair-tiles of 32 n-cols (exact)
constexpr int GRID = 512;                 // 2 blocks/CU, persistent (round-4 best)
constexpr int NWAVES = GRID * 4;          // 2048
constexpr int ZSTRIDE = 16;               // zbuf slots 64 B apart

typedef __attribute__((ext_vector_type(8))) __bf16 bf16x8;
typedef __attribute__((ext_vector_type(4))) float f32x4;
struct bf4 { __bf16 a, b, c, d; };

// A = mem rows (n), B = x rows (b).
// A-frag: A[n=lane&15][k=q*8+j]; B-frag: B[b=lane&15][k=q*8+j]
// C/D: col(b)=lane&15, row(n)=q*4+r   [HW-verified m89/m91]
// Round-4 win kept: each 128B out-line = two 64B nt stores back-to-back.
// Round-6 change: ALL x-fragments hoisted to registers (8mt x 4kc x 4VGPR
// = 128 VGPR) -> main loop has ZERO LDS reads (-384cy/tile issue). LDS xs
// is transient prologue staging only. Occupancy unchanged (2 wv/SIMD).
template<bool PASS2>
__global__ __launch_bounds__(256, 2) void nce_wave(
    const float* __restrict__ x,
    const int* __restrict__ labels,
    const float* __restrict__ mem_da,
    float* __restrict__ zbuf,
    float* __restrict__ out,
    float* __restrict__ maskout)
{
  __shared__ __bf16 xs[NB * LROW];   // 34816 B (prologue only)
  __shared__ float aux[NB];          // pass1: lbl_b; pass2: -log2(Z_b)
  __shared__ float zl[NB];           // pass1 block Z partials

  const int tid = threadIdx.x;

  // ---- one-time stage: x -> bf16 LDS (4 chunks of 4 float4: 16-reg spike) ----
  const float4* x4 = (const float4*)x;
  #pragma unroll
  for (int c = 0; c < 4; ++c) {
    float4 xv[4];
    #pragma unroll
    for (int i = 0; i < 4; ++i) xv[i] = x4[tid + (c * 4 + i) * 256];
    #pragma unroll
    for (int i = 0; i < 4; ++i) {
      int g4 = tid + (c * 4 + i) * 256;
      *(bf4*)&xs[(g4 >> 5) * LROW + (g4 & 31) * 4] =
          bf4{(__bf16)xv[i].x, (__bf16)xv[i].y, (__bf16)xv[i].z, (__bf16)xv[i].w};
    }
  }
  if (tid < NB) {
    if (PASS2) aux[tid] = -__log2f(zbuf[tid * ZSTRIDE]);
    else { aux[tid] = (float)labels[tid]; zl[tid] = 0.f; }
  }
  __syncthreads();                   // the ONLY barrier before the wave loop

  const int wid = tid >> 6, lane = tid & 63, q = lane >> 4, l16 = lane & 15;
  const int wgid = blockIdx.x * 4 + wid;

  // ---- hoist x fragments: one-time LDS -> 128 VGPRs, static indices ----
  bf16x8 xf[8][4];
  #pragma unroll
  for (int mt = 0; mt < 8; ++mt)
    #pragma unroll
    for (int kc = 0; kc < 4; ++kc)
      xf[mt][kc] = *(const bf16x8*)&xs[(mt * 16 + l16) * LROW + kc * 32 + q * 8];

  // per-lane b-row constants, hoisted: b = mt*16 + l16
  float lblb[8];
  #pragma unroll
  for (int mt = 0; mt < 8; ++mt) lblb[mt] = aux[mt * 16 + l16];

  float zacc[8];
  #pragma unroll
  for (int mt = 0; mt < 8; ++mt) zacc[mt] = 0.f;

  // ---- barrier-free wave loop over 32-col pair-tiles (1-2 per wave) ----
  for (int t = wgid; t < NTP; t += NWAVES) {
    // A fragments for BOTH halves staged once: 32 VGPRs
    bf16x8 ab[2][4];
    float ln[2];
    #pragma unroll
    for (int h = 0; h < 2; ++h) {
      const float* rowp = mem_da + (size_t)(t * 32 + h * 16 + l16) * 129;
      if (!PASS2) ln[h] = rowp[0];                              // bank label
      #pragma unroll
      for (int kc = 0; kc < 4; ++kc) {
        float tmp[8];
        __builtin_memcpy(tmp, rowp + 1 + kc * 32 + q * 8, 32);
        #pragma unroll
        for (int j = 0; j < 8; ++j) ab[h][kc][j] = (__bf16)tmp[j];
      }
    }

    // labels of the 32 n-rows live in lanes 0..15 of each 16-group
    float ml[2][4];
    if (!PASS2) {
      #pragma unroll
      for (int h = 0; h < 2; ++h)
        #pragma unroll
        for (int r = 0; r < 4; ++r) ml[h][r] = __shfl(ln[h], q * 4 + r, 16);
    }

    // ---- streamed mt: one acc pair live; x operand from registers ----
    #pragma unroll
    for (int mt = 0; mt < 8; ++mt) {
      f32x4 a0 = (f32x4){0.f, 0.f, 0.f, 0.f};
      f32x4 a1 = (f32x4){0.f, 0.f, 0.f, 0.f};
      #pragma unroll
      for (int kc = 0; kc < 4; ++kc) {
        a0 = __builtin_amdgcn_mfma_f32_16x16x32_bf16(ab[0][kc], xf[mt][kc], a0, 0, 0, 0);
        a1 = __builtin_amdgcn_mfma_f32_16x16x32_bf16(ab[1][kc], xf[mt][kc], a1, 0, 0, 0);
      }
      const size_t base = (size_t)(mt * 16 + l16) * NMEM + t * 32 + q * 4;
      if (!PASS2) {
        f32x4 mk0, mk1;
        float zs = 0.f;
        #pragma unroll
        for (int r = 0; r < 4; ++r) {
          zs += exp2f(a0[r] * K2);
          zs += exp2f(a1[r] * K2);
          mk0[r] = (ml[0][r] == lblb[mt]) ? 1.0f : 0.0f;
          mk1[r] = (ml[1][r] == lblb[mt]) ? 1.0f : 0.0f;
        }
        zacc[mt] += zs;
        __builtin_nontemporal_store(mk0, (f32x4*)&maskout[base]);
        __builtin_nontemporal_store(mk1, (f32x4*)&maskout[base + 16]);
      } else {
        f32x4 ov0, ov1;
        #pragma unroll
        for (int r = 0; r < 4; ++r) {
          ov0[r] = exp2f(__builtin_fmaf(a0[r], K2, lblb[mt]));
          ov1[r] = exp2f(__builtin_fmaf(a1[r], K2, lblb[mt]));
        }
        __builtin_nontemporal_store(ov0, (f32x4*)&out[base]);
        __builtin_nontemporal_store(ov1, (f32x4*)&out[base + 16]);
      }
    }
  }

  // ---- pass1 finalize: reduce over q-lanes (xor 16, 32) -> LDS -> global ----
  if (!PASS2) {
    #pragma unroll
    for (int mt = 0; mt < 8; ++mt) {
      float v = zacc[mt];
      v += __shfl_xor(v, 16);
      v += __shfl_xor(v, 32);
      if (lane < 16) atomicAdd(&zl[mt * 16 + lane], v);
    }
    __syncthreads();
    if (tid < NB) atomicAdd(&zbuf[tid * ZSTRIDE], zl[tid]);
  }
}

extern "C" void kernel_launch(void* const* d_in, const int* in_sizes, int n_in,
                              void* d_out, int out_size, void* d_ws, size_t ws_size,
                              hipStream_t stream) {
  const float* x      = (const float*)d_in[0];
  const int* labels   = (const int*)d_in[2];
  const float* mem_da = (const float*)d_in[3];
  float* out     = (float*)d_out;
  float* maskout = out + (size_t)NB * NMEM;
  float* zbuf    = (float*)d_ws;     // 128*16 floats = 8192 B

  hipMemsetAsync(zbuf, 0, NB * ZSTRIDE * sizeof(float), stream);
  nce_wave<false><<<GRID, 256, 0, stream>>>(x, labels, mem_da, zbuf, nullptr, maskout);
  nce_wave<true ><<<GRID, 256, 0, stream>>>(x, labels, mem_da, zbuf, out, nullptr);
}

// Round 7
// 219.734 us; speedup vs baseline: 1.0949x; 1.0386x over previous
//
#include <hip/hip_runtime.h>
#include <hip/hip_bf16.h>

#define NB 128        // batch B
#define NMEM 100000   // N
#define ND 128        // D
constexpr float K2 = 20.6099442241331655f;   // log2(e)/T  (T=0.07)

constexpr int LROW = ND + 8;              // xs LDS row: 136 bf16 = 272 B
constexpr int NTP = NMEM / 32;            // 3125 pair-tiles of 32 n-cols (exact)
constexpr int GRID = 1024;                // 4 blocks/CU resident: LDS 4*35.8=143KB<=160,
                                          // VGPR 16 waves*128=2048 pool. No churn (1024 slots).
constexpr int NWAVES = GRID * 4;          // 4096 waves >= 3125 tiles: one tile per wave
constexpr int ZSTRIDE = 16;               // zbuf slots 64 B apart
constexpr int RGRID = 2048;               // rescale grid

typedef __attribute__((ext_vector_type(8))) __bf16 bf16x8;
typedef __attribute__((ext_vector_type(4))) float f32x4;
struct bf4 { __bf16 a, b, c, d; };

// A = mem rows (n), B = x rows (b).
// A-frag: A[n=lane&15][k=q*8+j]; B-frag: B[b=lane&15][k=q*8+j]
// C/D: col(b)=lane&15, row(n)=q*4+r   [HW-verified m89/m91]
// Single heavy pass: computes mask AND exp2(s*K2) (nt stores, 128B-line-complete
// bursts per row: mk0,mk1 then e0,e1). Z accumulated from the same exp values.
// Normalization applied by the cheap streaming `rescale` kernel afterwards.
__global__ __launch_bounds__(256, 2) void nce_pass1(
    const float* __restrict__ x,
    const int* __restrict__ labels,
    const float* __restrict__ mem_da,
    float* __restrict__ zbuf,
    float* __restrict__ expout,
    float* __restrict__ maskout)
{
  // blocks with no tiles at all: exit before touching LDS/global
  if (blockIdx.x * 4 >= NTP) return;

  __shared__ __bf16 xs[NB * LROW];   // 34816 B
  __shared__ float aux[NB];          // lbl_b
  __shared__ float zl[NB];           // block Z partials

  const int tid = threadIdx.x;

  // ---- one-time stage: x -> bf16 LDS (4 chunks of 4 float4: 16-reg spike) ----
  const float4* x4 = (const float4*)x;
  #pragma unroll
  for (int c = 0; c < 4; ++c) {
    float4 xv[4];
    #pragma unroll
    for (int i = 0; i < 4; ++i) xv[i] = x4[tid + (c * 4 + i) * 256];
    #pragma unroll
    for (int i = 0; i < 4; ++i) {
      int g4 = tid + (c * 4 + i) * 256;
      *(bf4*)&xs[(g4 >> 5) * LROW + (g4 & 31) * 4] =
          bf4{(__bf16)xv[i].x, (__bf16)xv[i].y, (__bf16)xv[i].z, (__bf16)xv[i].w};
    }
  }
  if (tid < NB) { aux[tid] = (float)labels[tid]; zl[tid] = 0.f; }
  __syncthreads();                   // the ONLY barrier before finalize

  const int wid = tid >> 6, lane = tid & 63, q = lane >> 4, l16 = lane & 15;
  const int wgid = blockIdx.x * 4 + wid;

  // per-lane b-row constants: b = mt*16 + l16
  float lblb[8];
  #pragma unroll
  for (int mt = 0; mt < 8; ++mt) lblb[mt] = aux[mt * 16 + l16];

  float zacc[8];
  #pragma unroll
  for (int mt = 0; mt < 8; ++mt) zacc[mt] = 0.f;

  // ---- wave loop: exactly one pair-tile per wave (wgid >= NTP waves skip) ----
  for (int t = wgid; t < NTP; t += NWAVES) {
    f32x4 acc[2][8];                 // R4-measured-best h-phased structure
    float ln[2];

    #pragma unroll
    for (int h = 0; h < 2; ++h) {
      const float* rowp = mem_da + (size_t)(t * 32 + h * 16 + l16) * 129;
      ln[h] = rowp[0];               // bank label

      bf16x8 ab[4];
      #pragma unroll
      for (int kc = 0; kc < 4; ++kc) {
        float tmp[8];
        __builtin_memcpy(tmp, rowp + 1 + kc * 32 + q * 8, 32);
        #pragma unroll
        for (int j = 0; j < 8; ++j) ab[kc][j] = (__bf16)tmp[j];
      }

      #pragma unroll
      for (int mt = 0; mt < 8; ++mt) acc[h][mt] = (f32x4){0.f, 0.f, 0.f, 0.f};
      #pragma unroll
      for (int kc = 0; kc < 4; ++kc) {
        const int ko = kc * 32 + q * 8;
        #pragma unroll
        for (int mt = 0; mt < 8; ++mt) {
          bf16x8 xb = *(const bf16x8*)&xs[(mt * 16 + l16) * LROW + ko];
          acc[h][mt] = __builtin_amdgcn_mfma_f32_16x16x32_bf16(ab[kc], xb, acc[h][mt], 0, 0, 0);
        }
      }
    }

    // labels of the 32 n-rows live in lanes 0..15 of each 16-group
    float ml[2][4];
    #pragma unroll
    for (int h = 0; h < 2; ++h)
      #pragma unroll
      for (int r = 0; r < 4; ++r) ml[h][r] = __shfl(ln[h], q * 4 + r, 16);

    // ---- store burst: per row, both 64B halves back-to-back per buffer, nt ----
    #pragma unroll
    for (int mt = 0; mt < 8; ++mt) {
      const size_t base = (size_t)(mt * 16 + l16) * NMEM + t * 32 + q * 4;
      f32x4 mk0, mk1, e0, e1;
      float zs = 0.f;
      #pragma unroll
      for (int r = 0; r < 4; ++r) {
        e0[r] = exp2f(acc[0][mt][r] * K2);
        e1[r] = exp2f(acc[1][mt][r] * K2);
        zs += e0[r] + e1[r];
        mk0[r] = (ml[0][r] == lblb[mt]) ? 1.0f : 0.0f;
        mk1[r] = (ml[1][r] == lblb[mt]) ? 1.0f : 0.0f;
      }
      zacc[mt] += zs;
      __builtin_nontemporal_store(mk0, (f32x4*)&maskout[base]);
      __builtin_nontemporal_store(mk1, (f32x4*)&maskout[base + 16]);
      __builtin_nontemporal_store(e0, (f32x4*)&expout[base]);
      __builtin_nontemporal_store(e1, (f32x4*)&expout[base + 16]);
    }
  }

  // ---- finalize: reduce over q-lanes (xor 16, 32) -> LDS -> global ----
  #pragma unroll
  for (int mt = 0; mt < 8; ++mt) {
    float v = zacc[mt];
    v += __shfl_xor(v, 16);
    v += __shfl_xor(v, 32);
    if (lane < 16) atomicAdd(&zl[mt * 16 + lane], v);
  }
  __syncthreads();
  if (tid < NB) atomicAdd(&zbuf[tid * ZSTRIDE], zl[tid]);
}

// out[b][n] *= 1/Z[b] — pure coalesced stream, BW-bound (~102MB r+w)
__global__ __launch_bounds__(256) void rescale(
    float* __restrict__ out, const float* __restrict__ zbuf)
{
  __shared__ float sinv[NB];
  if (threadIdx.x < NB) sinv[threadIdx.x] = 1.0f / zbuf[threadIdx.x * ZSTRIDE];
  __syncthreads();

  constexpr int TOT4 = NB * NMEM / 4;      // 3,200,000 float4
  constexpr int ROW4 = NMEM / 4;           // 25,000 float4 per row
  const int stride = RGRID * 256;
  for (int i = blockIdx.x * 256 + threadIdx.x; i < TOT4; i += stride) {
    const float s = sinv[i / ROW4];
    f32x4 v = __builtin_nontemporal_load((const f32x4*)out + i);
    v[0] *= s; v[1] *= s; v[2] *= s; v[3] *= s;
    __builtin_nontemporal_store(v, (f32x4*)out + i);
  }
}

extern "C" void kernel_launch(void* const* d_in, const int* in_sizes, int n_in,
                              void* d_out, int out_size, void* d_ws, size_t ws_size,
                              hipStream_t stream) {
  const float* x      = (const float*)d_in[0];
  const int* labels   = (const int*)d_in[2];
  const float* mem_da = (const float*)d_in[3];
  float* out     = (float*)d_out;
  float* maskout = out + (size_t)NB * NMEM;
  float* zbuf    = (float*)d_ws;     // 128*16 floats = 8192 B

  hipMemsetAsync(zbuf, 0, NB * ZSTRIDE * sizeof(float), stream);
  nce_pass1<<<GRID, 256, 0, stream>>>(x, labels, mem_da, zbuf, out, maskout);
  rescale<<<RGRID, 256, 0, stream>>>(out, zbuf);
}